// Round 1
// baseline (473.835 us; speedup 1.0000x reference)
//
#include <hip/hip_runtime.h>
#include <math.h>

#define DT 0.01f

// ---------------------------------------------------------------------------
// Pass 1: histogram of body indices (the ONLY random-access traffic: 4B RMW).
// ---------------------------------------------------------------------------
__global__ void k_hist(const int* __restrict__ fromb, const int* __restrict__ tob,
                       int nc, int* __restrict__ count) {
    const int total4 = nc >> 2;           // int4 chunks per array
    const int tid = blockIdx.x * blockDim.x + threadIdx.x;
    const int nthreads = gridDim.x * blockDim.x;
    for (int q = tid; q < 2 * total4; q += nthreads) {
        int4 v;
        if (q < total4) v = ((const int4*)fromb)[q];
        else            v = ((const int4*)tob)[q - total4];
        atomicAdd(&count[v.x], 1);
        atomicAdd(&count[v.y], 1);
        atomicAdd(&count[v.z], 1);
        atomicAdd(&count[v.w], 1);
    }
    // generic tail (nc % 4 != 0); no-op for NC = 2^21
    const int tail = nc & 3;
    if (tail && tid < 2 * tail) {
        const int base = nc - tail;
        const int idx = (tid < tail) ? fromb[base + tid] : tob[base + (tid - tail)];
        atomicAdd(&count[idx], 1);
    }
}

// ---------------------------------------------------------------------------
// Pass 2: one sequential pass over bodies. Compute f(b) (world-frame anchor),
// accumulate count*m*f into 3 double sums, store f(b) (inf sentinel if
// untouched) for pass 3.
// ---------------------------------------------------------------------------
__global__ void k_reduce(const float2* __restrict__ pos, const float* __restrict__ ang,
                         const float* __restrict__ mass,
                         const float2* __restrict__ fpos, const float2* __restrict__ tpos,
                         const int* __restrict__ count, float2* __restrict__ fout,
                         double* __restrict__ sums, int n, int nc) {
    double wx = 0.0, wy = 0.0, wm = 0.0;
    const int tid = blockIdx.x * blockDim.x + threadIdx.x;
    const int stride = gridDim.x * blockDim.x;
    const float inf = __uint_as_float(0x7f800000u);
    for (int b = tid; b < n; b += stride) {
        const int c = count[b];
        float2 f;
        if (c > 0) {
            const float2 p = pos[b];
            const float a = ang[b] - 1.57079632679489661923f;  // angle - pi/2
            const float m = mass[b];
            const float2 r = (b < nc) ? fpos[b] : tpos[b - nc];
            const float ca = cosf(a), sa = sinf(a);
            f.x = ca * r.x - sa * r.y + p.x;
            f.y = sa * r.x + ca * r.y + p.y;
            const double cm = (double)c * (double)m;
            wx += cm * (double)f.x;
            wy += cm * (double)f.y;
            wm += cm;
        } else {
            f.x = inf; f.y = inf;   // sentinel: body never referenced
        }
        fout[b] = f;
    }
    // wave (64-lane) shuffle reduction, then cross-wave via LDS
    for (int off = 32; off > 0; off >>= 1) {
        wx += __shfl_down(wx, off);
        wy += __shfl_down(wy, off);
        wm += __shfl_down(wm, off);
    }
    __shared__ double swx[4], swy[4], swm[4];
    const int lane = threadIdx.x & 63, wave = threadIdx.x >> 6;
    if (lane == 0) { swx[wave] = wx; swy[wave] = wy; swm[wave] = wm; }
    __syncthreads();
    if (threadIdx.x == 0) {
        double tx = 0.0, ty = 0.0, tm = 0.0;
        const int nw = blockDim.x >> 6;
        for (int w = 0; w < nw; ++w) { tx += swx[w]; ty += swy[w]; tm += swm[w]; }
        atomicAdd(&sums[0], tx);
        atomicAdd(&sums[1], ty);
        atomicAdd(&sums[2], tm);
    }
}

// ---------------------------------------------------------------------------
// Pass 3: out[b] = velocity[b] + (touched ? stiffness*DT*(target - f(b)) : 0).
// Fully coalesced float4 (2 bodies per thread).
// ---------------------------------------------------------------------------
__global__ void k_apply(const float4* __restrict__ f, const float4* __restrict__ vel,
                        const double* __restrict__ sums, const float* __restrict__ stiff,
                        float4* __restrict__ out, int n2) {
    const int q = blockIdx.x * blockDim.x + threadIdx.x;
    if (q >= n2) return;
    const double tm = sums[2];
    const float tx = (float)(sums[0] / tm);
    const float ty = (float)(sums[1] / tm);
    const float sdt = (*stiff) * DT;
    const unsigned INFBITS = 0x7f800000u;
    const float4 fv = f[q];
    float4 o = vel[q];
    if (__float_as_uint(fv.x) != INFBITS) {
        o.x += sdt * (tx - fv.x);
        o.y += sdt * (ty - fv.y);
    }
    if (__float_as_uint(fv.z) != INFBITS) {
        o.z += sdt * (tx - fv.z);
        o.w += sdt * (ty - fv.w);
    }
    out[q] = o;
}

// ---------------------------------------------------------------------------
// Launch
// Inputs (setup_inputs order):
//  0 from_bodies            int32  [NC]
//  1 to_bodies              int32  [NC]
//  2 from_bodies_position   f32    [NC,2]
//  3 to_bodies_position     f32    [NC,2]
//  4 stiffness              f32    [1]
//  5 position               f32    [N,2]
//  6 angle                  f32    [N]
//  7 mass                   f32    [N]
//  8 velocity               f32    [N,2]
// Output: velocity + to_apply, f32 [N,2]
// ---------------------------------------------------------------------------
extern "C" void kernel_launch(void* const* d_in, const int* in_sizes, int n_in,
                              void* d_out, int out_size, void* d_ws, size_t ws_size,
                              hipStream_t stream) {
    const int NC = in_sizes[0];
    const int N  = in_sizes[7];   // mass has N elements

    const int* fromb = (const int*)d_in[0];
    const int* tob   = (const int*)d_in[1];
    const float2* fpos = (const float2*)d_in[2];
    const float2* tpos = (const float2*)d_in[3];
    const float* stiff = (const float*)d_in[4];
    const float2* pos  = (const float2*)d_in[5];
    const float* ang   = (const float*)d_in[6];
    const float* mass  = (const float*)d_in[7];
    const float2* vel  = (const float2*)d_in[8];

    // ws layout: [0,24) double sums[3]; [64, 64+4N) int count[N];
    //            [64+4N, 64+12N) float2 f[N]
    char* ws = (char*)d_ws;
    double* sums = (double*)ws;
    int* count   = (int*)(ws + 64);
    float2* fbuf = (float2*)(ws + 64 + (size_t)N * sizeof(int));

    // zero counts + sums (ws is poisoned 0xAA before every launch)
    hipMemsetAsync(d_ws, 0, 64 + (size_t)N * sizeof(int), stream);

    const int BT = 256;
    // pass 1: 2*(NC/4) int4 chunks
    {
        int work = 2 * (NC >> 2);
        int blocks = (work + BT - 1) / BT;
        if (blocks > 4096) blocks = 4096;
        k_hist<<<blocks, BT, 0, stream>>>(fromb, tob, NC, count);
    }
    // pass 2: grid-stride over N bodies, ~4 bodies/thread
    {
        int blocks = 4096;
        k_reduce<<<blocks, BT, 0, stream>>>(pos, ang, mass, fpos, tpos,
                                            count, fbuf, sums, N, NC);
    }
    // pass 3: 2 bodies per thread (float4)
    {
        int n2 = N >> 1;
        int blocks = (n2 + BT - 1) / BT;
        k_apply<<<blocks, BT, 0, stream>>>((const float4*)fbuf, (const float4*)vel,
                                           sums, stiff, (float4*)d_out, n2);
    }
}

// Round 2
// 464.136 us; speedup vs baseline: 1.0209x; 1.0209x over previous
//
#include <hip/hip_runtime.h>
#include <math.h>

#define DT 0.01f

// ---------------------------------------------------------------------------
// Pass 1: histogram of body indices (the ONLY random-access traffic: 4B RMW).
// ---------------------------------------------------------------------------
__global__ void k_hist(const int* __restrict__ fromb, const int* __restrict__ tob,
                       int nc, int* __restrict__ count) {
    const int total4 = nc >> 2;           // int4 chunks per array
    const int tid = blockIdx.x * blockDim.x + threadIdx.x;
    const int nthreads = gridDim.x * blockDim.x;
    for (int q = tid; q < 2 * total4; q += nthreads) {
        int4 v;
        if (q < total4) v = ((const int4*)fromb)[q];
        else            v = ((const int4*)tob)[q - total4];
        atomicAdd(&count[v.x], 1);
        atomicAdd(&count[v.y], 1);
        atomicAdd(&count[v.z], 1);
        atomicAdd(&count[v.w], 1);
    }
    const int tail = nc & 3;              // no-op for NC = 2^21
    if (tail && tid < 2 * tail) {
        const int base = nc - tail;
        const int idx = (tid < tail) ? fromb[base + tid] : tob[base + (tid - tail)];
        atomicAdd(&count[idx], 1);
    }
}

// ---------------------------------------------------------------------------
// Pass 2: branch-free, fully vectorized. 4 bodies/thread, 7 independent
// 16B loads issued up-front (no data-dependent branch before loads).
// f computed unconditionally; weight c*m is 0 for untouched bodies.
// Sentinel (+inf) selected branchlessly for the apply pass.
// ---------------------------------------------------------------------------
__global__ void k_reduce(const float4* __restrict__ pos4, const float4* __restrict__ ang_,
                         const float4* __restrict__ mass4,
                         const float4* __restrict__ fpos4, const float4* __restrict__ tpos4,
                         const int4* __restrict__ count4, float4* __restrict__ fout4,
                         double* __restrict__ sums, int n, int nc) {
    const int tid = blockIdx.x * blockDim.x + threadIdx.x;
    const int base = tid << 2;            // 4 bodies per thread
    double wx = 0.0, wy = 0.0, wm = 0.0;
    const float inf = __uint_as_float(0x7f800000u);

    if (base + 3 < n) {
        // all 7 loads independent -> issue together
        const int4   c4  = count4[tid];
        const float4 p01 = pos4[2 * tid];
        const float4 p23 = pos4[2 * tid + 1];
        const float4 a4  = ang_[tid];
        const float4 m4  = mass4[tid];
        // nc divisible by 4 -> a 4-body group never straddles fpos/tpos
        const float4* rp = (base < nc) ? (fpos4 + 2 * tid) : (tpos4 + 2 * (tid - (nc >> 2)));
        const float4 r01 = rp[0];
        const float4 r23 = rp[1];

        float fx[4], fy[4];
        const float px[4] = {p01.x, p01.z, p23.x, p23.z};
        const float py[4] = {p01.y, p01.w, p23.y, p23.w};
        const float rx[4] = {r01.x, r01.z, r23.x, r23.z};
        const float ry[4] = {r01.y, r01.w, r23.y, r23.w};
        const float aa[4] = {a4.x, a4.y, a4.z, a4.w};
        const float mm[4] = {m4.x, m4.y, m4.z, m4.w};
        const int   cc[4] = {c4.x, c4.y, c4.z, c4.w};

        #pragma unroll
        for (int k = 0; k < 4; ++k) {
            const float a = aa[k] - 1.57079632679489661923f;
            const float ca = __cosf(a), sa = __sinf(a);
            fx[k] = ca * rx[k] - sa * ry[k] + px[k];
            fy[k] = sa * rx[k] + ca * ry[k] + py[k];
            const double cm = (double)cc[k] * (double)mm[k];   // 0 when untouched
            wx += cm * (double)fx[k];
            wy += cm * (double)fy[k];
            wm += cm;
        }
        // branchless sentinel for apply
        float4 o01, o23;
        o01.x = cc[0] ? fx[0] : inf;  o01.y = cc[0] ? fy[0] : inf;
        o01.z = cc[1] ? fx[1] : inf;  o01.w = cc[1] ? fy[1] : inf;
        o23.x = cc[2] ? fx[2] : inf;  o23.y = cc[2] ? fy[2] : inf;
        o23.z = cc[3] ? fx[3] : inf;  o23.w = cc[3] ? fy[3] : inf;
        fout4[2 * tid]     = o01;
        fout4[2 * tid + 1] = o23;
    } else if (base < n) {
        // generic scalar tail (not hit for N = 4M)
        const int* count = (const int*)count4;
        const float2* pos = (const float2*)pos4;
        const float* ang = (const float*)ang_;
        const float* mass = (const float*)mass4;
        const float2* fpos = (const float2*)fpos4;
        const float2* tpos = (const float2*)tpos4;
        float2* fout = (float2*)fout4;
        for (int b = base; b < n; ++b) {
            const int c = count[b];
            const float2 p = pos[b];
            const float a = ang[b] - 1.57079632679489661923f;
            const float m = mass[b];
            const float2 r = (b < nc) ? fpos[b] : tpos[b - nc];
            const float ca = __cosf(a), sa = __sinf(a);
            const float gx = ca * r.x - sa * r.y + p.x;
            const float gy = sa * r.x + ca * r.y + p.y;
            const double cm = (double)c * (double)m;
            wx += cm * (double)gx; wy += cm * (double)gy; wm += cm;
            float2 o; o.x = c ? gx : inf; o.y = c ? gy : inf;
            fout[b] = o;
        }
    }

    // wave (64-lane) shuffle reduction, then cross-wave via LDS
    for (int off = 32; off > 0; off >>= 1) {
        wx += __shfl_down(wx, off);
        wy += __shfl_down(wy, off);
        wm += __shfl_down(wm, off);
    }
    __shared__ double swx[4], swy[4], swm[4];
    const int lane = threadIdx.x & 63, wave = threadIdx.x >> 6;
    if (lane == 0) { swx[wave] = wx; swy[wave] = wy; swm[wave] = wm; }
    __syncthreads();
    if (threadIdx.x == 0) {
        double tx = 0.0, ty = 0.0, tm = 0.0;
        const int nw = blockDim.x >> 6;
        for (int w = 0; w < nw; ++w) { tx += swx[w]; ty += swy[w]; tm += swm[w]; }
        atomicAdd(&sums[0], tx);
        atomicAdd(&sums[1], ty);
        atomicAdd(&sums[2], tm);
    }
}

// ---------------------------------------------------------------------------
// Pass 3: out[b] = velocity[b] + (touched ? stiffness*DT*(target - f(b)) : 0).
// Fully coalesced float4 (2 bodies per thread).
// ---------------------------------------------------------------------------
__global__ void k_apply(const float4* __restrict__ f, const float4* __restrict__ vel,
                        const double* __restrict__ sums, const float* __restrict__ stiff,
                        float4* __restrict__ out, int n2) {
    const int q = blockIdx.x * blockDim.x + threadIdx.x;
    if (q >= n2) return;
    const double tm = sums[2];
    const float tx = (float)(sums[0] / tm);
    const float ty = (float)(sums[1] / tm);
    const float sdt = (*stiff) * DT;
    const unsigned INFBITS = 0x7f800000u;
    const float4 fv = f[q];
    float4 o = vel[q];
    if (__float_as_uint(fv.x) != INFBITS) {
        o.x += sdt * (tx - fv.x);
        o.y += sdt * (ty - fv.y);
    }
    if (__float_as_uint(fv.z) != INFBITS) {
        o.z += sdt * (tx - fv.z);
        o.w += sdt * (ty - fv.w);
    }
    out[q] = o;
}

// ---------------------------------------------------------------------------
// Launch.  Inputs (setup_inputs order):
//  0 from_bodies int32[NC]  1 to_bodies int32[NC]
//  2 from_bodies_position f32[NC,2]  3 to_bodies_position f32[NC,2]
//  4 stiffness f32[1]  5 position f32[N,2]  6 angle f32[N]
//  7 mass f32[N]  8 velocity f32[N,2]      Output: f32[N,2]
// ---------------------------------------------------------------------------
extern "C" void kernel_launch(void* const* d_in, const int* in_sizes, int n_in,
                              void* d_out, int out_size, void* d_ws, size_t ws_size,
                              hipStream_t stream) {
    const int NC = in_sizes[0];
    const int N  = in_sizes[7];   // mass has N elements

    const int* fromb = (const int*)d_in[0];
    const int* tob   = (const int*)d_in[1];
    const float* stiff = (const float*)d_in[4];

    // ws layout: [0,24) double sums[3]; [64, 64+4N) int count[N];
    //            [64+4N, 64+12N) float2 f[N]
    char* ws = (char*)d_ws;
    double* sums = (double*)ws;
    int* count   = (int*)(ws + 64);
    float2* fbuf = (float2*)(ws + 64 + (size_t)N * sizeof(int));

    hipMemsetAsync(d_ws, 0, 64 + (size_t)N * sizeof(int), stream);

    const int BT = 256;
    // pass 1: 2*(NC/4) int4 chunks, 1 chunk/thread
    {
        int work = 2 * (NC >> 2);
        int blocks = (work + BT - 1) / BT;
        if (blocks > 4096) blocks = 4096;
        k_hist<<<blocks, BT, 0, stream>>>(fromb, tob, NC, count);
    }
    // pass 2: 4 bodies/thread, branch-free vectorized
    {
        int threads = (N + 3) >> 2;
        int blocks = (threads + BT - 1) / BT;
        k_reduce<<<blocks, BT, 0, stream>>>(
            (const float4*)d_in[5], (const float4*)d_in[6], (const float4*)d_in[7],
            (const float4*)d_in[2], (const float4*)d_in[3],
            (const int4*)count, (float4*)fbuf, sums, N, NC);
    }
    // pass 3: 2 bodies per thread (float4)
    {
        int n2 = N >> 1;
        int blocks = (n2 + BT - 1) / BT;
        k_apply<<<blocks, BT, 0, stream>>>((const float4*)fbuf, (const float4*)d_in[8],
                                           sums, stiff, (float4*)d_out, n2);
    }
}

// Round 3
// 316.165 us; speedup vs baseline: 1.4987x; 1.4680x over previous
//
#include <hip/hip_runtime.h>
#include <hip/hip_fp16.h>
#include <math.h>

#define DT 0.01f
#define PI_2F 1.57079632679489661923f
#define BT 256
#define GATHER_BLOCKS 2048

// ---------------------------------------------------------------------------
// Pass 1 (k_prep): sequential pass over bodies. Compute f(b) = R(ang-pi/2)*rel + pos,
// pack (f16 fx, f16 fy, f16 m) into 8 bytes -> fbuf (32 MB, ~L2-resident).
// The f16 table is ONLY used for the target reduction (error averages out over
// 4.19M terms); pass 4 recomputes f in exact f32.
// ---------------------------------------------------------------------------
__global__ void k_prep(const float4* __restrict__ pos4, const float4* __restrict__ ang4,
                       const float4* __restrict__ mass4,
                       const float4* __restrict__ fpos4, const float4* __restrict__ tpos4,
                       uint2* __restrict__ fbuf, int n, int nc) {
    const int tid = blockIdx.x * blockDim.x + threadIdx.x;
    const int base = tid << 2;
    if (base + 3 < n) {
        const float4 p01 = pos4[2 * tid], p23 = pos4[2 * tid + 1];
        const float4 a4 = ang4[tid], m4 = mass4[tid];
        const float4* rp = (base < nc) ? (fpos4 + 2 * tid) : (tpos4 + 2 * (tid - (nc >> 2)));
        const float4 r01 = rp[0], r23 = rp[1];
        const float px[4] = {p01.x, p01.z, p23.x, p23.z};
        const float py[4] = {p01.y, p01.w, p23.y, p23.w};
        const float rx[4] = {r01.x, r01.z, r23.x, r23.z};
        const float ry[4] = {r01.y, r01.w, r23.y, r23.w};
        const float aa[4] = {a4.x, a4.y, a4.z, a4.w};
        const float mm[4] = {m4.x, m4.y, m4.z, m4.w};
        unsigned lo[4], hi[4];
        #pragma unroll
        for (int k = 0; k < 4; ++k) {
            const float a = aa[k] - PI_2F;
            const float ca = __cosf(a), sa = __sinf(a);
            const float fx = ca * rx[k] - sa * ry[k] + px[k];
            const float fy = sa * rx[k] + ca * ry[k] + py[k];
            lo[k] = (unsigned)__half_as_ushort(__float2half(fx)) |
                    ((unsigned)__half_as_ushort(__float2half(fy)) << 16);
            hi[k] = (unsigned)__half_as_ushort(__float2half(mm[k]));
        }
        uint4* o = (uint4*)fbuf;
        o[2 * tid]     = make_uint4(lo[0], hi[0], lo[1], hi[1]);
        o[2 * tid + 1] = make_uint4(lo[2], hi[2], lo[3], hi[3]);
    } else if (base < n) {
        const float2* pos = (const float2*)pos4;
        const float* ang = (const float*)ang4;
        const float* mass = (const float*)mass4;
        const float2* fpos = (const float2*)fpos4;
        const float2* tpos = (const float2*)tpos4;
        for (int b = base; b < n; ++b) {
            const float2 p = pos[b];
            const float a = ang[b] - PI_2F;
            const float m = mass[b];
            const float2 r = (b < nc) ? fpos[b] : tpos[b - nc];
            const float ca = __cosf(a), sa = __sinf(a);
            const float fx = ca * r.x - sa * r.y + p.x;
            const float fy = sa * r.x + ca * r.y + p.y;
            uint2 e;
            e.x = (unsigned)__half_as_ushort(__float2half(fx)) |
                  ((unsigned)__half_as_ushort(__float2half(fy)) << 16);
            e.y = (unsigned)__half_as_ushort(__float2half(m));
            fbuf[b] = e;
        }
    }
}

// ---------------------------------------------------------------------------
// Pass 2 (k_gather): per endpoint, ONE 8B read-only random gather (no RMW)
// + benign same-value byte store flags[idx]=1. Accumulate m*f in doubles,
// per-block partial to ws (no same-address atomic contention).
// ---------------------------------------------------------------------------
__device__ __forceinline__ void unpack_acc(uint2 e, double& wx, double& wy, double& wm) {
    const float fx = __half2float(__ushort_as_half((unsigned short)(e.x & 0xffff)));
    const float fy = __half2float(__ushort_as_half((unsigned short)(e.x >> 16)));
    const float m  = __half2float(__ushort_as_half((unsigned short)(e.y & 0xffff)));
    wx += (double)(m * fx);
    wy += (double)(m * fy);
    wm += (double)m;
}

__global__ void k_gather(const int* __restrict__ fromb, const int* __restrict__ tob,
                         int nc, const uint2* __restrict__ fbuf,
                         unsigned char* __restrict__ flags,
                         double* __restrict__ partials) {
    const int total4 = nc >> 2;
    const int tid = blockIdx.x * blockDim.x + threadIdx.x;
    const int nth = gridDim.x * blockDim.x;
    double wx = 0.0, wy = 0.0, wm = 0.0;
    for (int q = tid; q < 2 * total4; q += nth) {
        const int4 v = (q < total4) ? ((const int4*)fromb)[q]
                                    : ((const int4*)tob)[q - total4];
        // 4 independent gathers in flight
        const uint2 e0 = fbuf[v.x];
        const uint2 e1 = fbuf[v.y];
        const uint2 e2 = fbuf[v.z];
        const uint2 e3 = fbuf[v.w];
        flags[v.x] = 1; flags[v.y] = 1; flags[v.z] = 1; flags[v.w] = 1;
        unpack_acc(e0, wx, wy, wm);
        unpack_acc(e1, wx, wy, wm);
        unpack_acc(e2, wx, wy, wm);
        unpack_acc(e3, wx, wy, wm);
    }
    const int tail = nc & 3;              // no-op for NC = 2^21
    if (tail && tid < 2 * tail) {
        const int base = nc - tail;
        const int idx = (tid < tail) ? fromb[base + tid] : tob[base + (tid - tail)];
        const uint2 e = fbuf[idx];
        flags[idx] = 1;
        unpack_acc(e, wx, wy, wm);
    }
    // wave shuffle reduction + cross-wave LDS
    for (int off = 32; off > 0; off >>= 1) {
        wx += __shfl_down(wx, off);
        wy += __shfl_down(wy, off);
        wm += __shfl_down(wm, off);
    }
    __shared__ double swx[4], swy[4], swm[4];
    const int lane = threadIdx.x & 63, wave = threadIdx.x >> 6;
    if (lane == 0) { swx[wave] = wx; swy[wave] = wy; swm[wave] = wm; }
    __syncthreads();
    if (threadIdx.x == 0) {
        double tx = 0.0, ty = 0.0, tm = 0.0;
        const int nw = blockDim.x >> 6;
        for (int w = 0; w < nw; ++w) { tx += swx[w]; ty += swy[w]; tm += swm[w]; }
        partials[3 * blockIdx.x]     = tx;
        partials[3 * blockIdx.x + 1] = ty;
        partials[3 * blockIdx.x + 2] = tm;
    }
}

// ---------------------------------------------------------------------------
// Pass 3 (k_final): reduce the block partials, write target = sum/m_sum as
// float2 (keeps the fp64 divide out of the big apply pass).
// ---------------------------------------------------------------------------
__global__ void k_final(const double* __restrict__ partials, int nparts,
                        float2* __restrict__ target) {
    double sx = 0.0, sy = 0.0, sm = 0.0;
    for (int i = threadIdx.x; i < nparts; i += blockDim.x) {
        sx += partials[3 * i];
        sy += partials[3 * i + 1];
        sm += partials[3 * i + 2];
    }
    for (int off = 32; off > 0; off >>= 1) {
        sx += __shfl_down(sx, off);
        sy += __shfl_down(sy, off);
        sm += __shfl_down(sm, off);
    }
    __shared__ double swx[4], swy[4], swm[4];
    const int lane = threadIdx.x & 63, wave = threadIdx.x >> 6;
    if (lane == 0) { swx[wave] = sx; swy[wave] = sy; swm[wave] = sm; }
    __syncthreads();
    if (threadIdx.x == 0) {
        double tx = 0.0, ty = 0.0, tm = 0.0;
        const int nw = blockDim.x >> 6;
        for (int w = 0; w < nw; ++w) { tx += swx[w]; ty += swy[w]; tm += swm[w]; }
        float2 t;
        t.x = (float)(tx / tm);
        t.y = (float)(ty / tm);
        *target = t;
    }
}

// ---------------------------------------------------------------------------
// Pass 4 (k_apply): recompute f(b) exactly in f32 (output precision does not
// depend on the f16 table), out = vel + (flag ? sdt*(target-f) : 0).
// Fully coalesced, 4 bodies/thread.
// ---------------------------------------------------------------------------
__global__ void k_apply(const float4* __restrict__ pos4, const float4* __restrict__ ang4,
                        const float4* __restrict__ fpos4, const float4* __restrict__ tpos4,
                        const float4* __restrict__ vel4,
                        const unsigned char* __restrict__ flags,
                        const float2* __restrict__ target, const float* __restrict__ stiff,
                        float4* __restrict__ out4, int n, int nc) {
    const int tid = blockIdx.x * blockDim.x + threadIdx.x;
    const int base = tid << 2;
    if (base + 3 < n) {
        const float4 p01 = pos4[2 * tid], p23 = pos4[2 * tid + 1];
        const float4 a4 = ang4[tid];
        const float4* rp = (base < nc) ? (fpos4 + 2 * tid) : (tpos4 + 2 * (tid - (nc >> 2)));
        const float4 r01 = rp[0], r23 = rp[1];
        const float4 v01 = vel4[2 * tid], v23 = vel4[2 * tid + 1];
        const unsigned fl = *(const unsigned*)(flags + base);   // 4 flag bytes
        const float2 t = *target;
        const float sdt = (*stiff) * DT;

        const float px[4] = {p01.x, p01.z, p23.x, p23.z};
        const float py[4] = {p01.y, p01.w, p23.y, p23.w};
        const float rx[4] = {r01.x, r01.z, r23.x, r23.z};
        const float ry[4] = {r01.y, r01.w, r23.y, r23.w};
        const float aa[4] = {a4.x, a4.y, a4.z, a4.w};
        float ox[4], oy[4];
        const float vx[4] = {v01.x, v01.z, v23.x, v23.z};
        const float vy[4] = {v01.y, v01.w, v23.y, v23.w};
        #pragma unroll
        for (int k = 0; k < 4; ++k) {
            const float a = aa[k] - PI_2F;
            const float ca = __cosf(a), sa = __sinf(a);
            const float fx = ca * rx[k] - sa * ry[k] + px[k];
            const float fy = sa * rx[k] + ca * ry[k] + py[k];
            const bool touched = ((fl >> (8 * k)) & 0xff) != 0;
            ox[k] = vx[k] + (touched ? sdt * (t.x - fx) : 0.0f);
            oy[k] = vy[k] + (touched ? sdt * (t.y - fy) : 0.0f);
        }
        out4[2 * tid]     = make_float4(ox[0], oy[0], ox[1], oy[1]);
        out4[2 * tid + 1] = make_float4(ox[2], oy[2], ox[3], oy[3]);
    } else if (base < n) {
        const float2* pos = (const float2*)pos4;
        const float* ang = (const float*)ang4;
        const float2* fpos = (const float2*)fpos4;
        const float2* tpos = (const float2*)tpos4;
        const float2* vel = (const float2*)vel4;
        float2* out = (float2*)out4;
        const float2 t = *target;
        const float sdt = (*stiff) * DT;
        for (int b = base; b < n; ++b) {
            const float2 p = pos[b];
            const float a = ang[b] - PI_2F;
            const float2 r = (b < nc) ? fpos[b] : tpos[b - nc];
            const float ca = __cosf(a), sa = __sinf(a);
            const float fx = ca * r.x - sa * r.y + p.x;
            const float fy = sa * r.x + ca * r.y + p.y;
            float2 o = vel[b];
            if (flags[b]) { o.x += sdt * (t.x - fx); o.y += sdt * (t.y - fy); }
            out[b] = o;
        }
    }
}

// ---------------------------------------------------------------------------
// Launch.  Inputs (setup_inputs order):
//  0 from_bodies int32[NC]  1 to_bodies int32[NC]
//  2 from_bodies_position f32[NC,2]  3 to_bodies_position f32[NC,2]
//  4 stiffness f32[1]  5 position f32[N,2]  6 angle f32[N]
//  7 mass f32[N]  8 velocity f32[N,2]      Output: f32[N,2]
//
// ws layout: [0,8)    float2 target
//            [64, 64+49152)           double partials[GATHER_BLOCKS*3]
//            [49216, 49216+8N)        uint2 fbuf[N]     (f16 fx,fy,m)
//            [49216+8N, 49216+9N)     uchar flags[N]
// total ~ 37.8 MB (previous rounds used 48 MB of ws successfully)
// ---------------------------------------------------------------------------
extern "C" void kernel_launch(void* const* d_in, const int* in_sizes, int n_in,
                              void* d_out, int out_size, void* d_ws, size_t ws_size,
                              hipStream_t stream) {
    const int NC = in_sizes[0];
    const int N  = in_sizes[7];   // mass has N elements

    char* ws = (char*)d_ws;
    float2* target   = (float2*)ws;
    double* partials = (double*)(ws + 64);
    uint2*  fbuf     = (uint2*)(ws + 64 + (size_t)GATHER_BLOCKS * 3 * sizeof(double));
    unsigned char* flags = (unsigned char*)((char*)fbuf + (size_t)N * sizeof(uint2));

    // zero only the flags (4 MB); partials/target are written unconditionally
    hipMemsetAsync(flags, 0, (size_t)N, stream);

    // pass 1: build the f16 gather table
    {
        int threads = (N + 3) >> 2;
        int blocks = (threads + BT - 1) / BT;
        k_prep<<<blocks, BT, 0, stream>>>(
            (const float4*)d_in[5], (const float4*)d_in[6], (const float4*)d_in[7],
            (const float4*)d_in[2], (const float4*)d_in[3], fbuf, N, NC);
    }
    // pass 2: gather + flag scatter + partial sums
    k_gather<<<GATHER_BLOCKS, BT, 0, stream>>>(
        (const int*)d_in[0], (const int*)d_in[1], NC, fbuf, flags, partials);
    // pass 3: final reduce -> target
    k_final<<<1, BT, 0, stream>>>(partials, GATHER_BLOCKS, target);
    // pass 4: apply
    {
        int threads = (N + 3) >> 2;
        int blocks = (threads + BT - 1) / BT;
        k_apply<<<blocks, BT, 0, stream>>>(
            (const float4*)d_in[5], (const float4*)d_in[6],
            (const float4*)d_in[2], (const float4*)d_in[3],
            (const float4*)d_in[8], flags, (const float2*)target,
            (const float*)d_in[4], (float4*)d_out, N, NC);
    }
}

// Round 4
// 315.442 us; speedup vs baseline: 1.5021x; 1.0023x over previous
//
#include <hip/hip_runtime.h>
#include <hip/hip_fp16.h>
#include <math.h>

#define DT 0.01f
#define PI_2F 1.57079632679489661923f
#define BT 256
#define GATHER_BLOCKS 1024   // 1024*256 threads * 16 endpoints = 8.39M: exact cover

// ---------------------------------------------------------------------------
// Pass 1 (k_prep): sequential pass over bodies. Compute f(b), pack
// (f16 fx, f16 fy, f16 m) into 8 bytes -> fbuf (32 MB, LLC-resident).
// Pass 4 recomputes f in exact f32; the f16 table only feeds the target sum.
// ---------------------------------------------------------------------------
__global__ void k_prep(const float4* __restrict__ pos4, const float4* __restrict__ ang4,
                       const float4* __restrict__ mass4,
                       const float4* __restrict__ fpos4, const float4* __restrict__ tpos4,
                       uint2* __restrict__ fbuf, int n, int nc) {
    const int tid = blockIdx.x * blockDim.x + threadIdx.x;
    const int base = tid << 2;
    if (base + 3 < n) {
        const float4 p01 = pos4[2 * tid], p23 = pos4[2 * tid + 1];
        const float4 a4 = ang4[tid], m4 = mass4[tid];
        const float4* rp = (base < nc) ? (fpos4 + 2 * tid) : (tpos4 + 2 * (tid - (nc >> 2)));
        const float4 r01 = rp[0], r23 = rp[1];
        const float px[4] = {p01.x, p01.z, p23.x, p23.z};
        const float py[4] = {p01.y, p01.w, p23.y, p23.w};
        const float rx[4] = {r01.x, r01.z, r23.x, r23.z};
        const float ry[4] = {r01.y, r01.w, r23.y, r23.w};
        const float aa[4] = {a4.x, a4.y, a4.z, a4.w};
        const float mm[4] = {m4.x, m4.y, m4.z, m4.w};
        unsigned lo[4], hi[4];
        #pragma unroll
        for (int k = 0; k < 4; ++k) {
            const float a = aa[k] - PI_2F;
            const float ca = __cosf(a), sa = __sinf(a);
            const float fx = ca * rx[k] - sa * ry[k] + px[k];
            const float fy = sa * rx[k] + ca * ry[k] + py[k];
            lo[k] = (unsigned)__half_as_ushort(__float2half(fx)) |
                    ((unsigned)__half_as_ushort(__float2half(fy)) << 16);
            hi[k] = (unsigned)__half_as_ushort(__float2half(mm[k]));
        }
        uint4* o = (uint4*)fbuf;
        o[2 * tid]     = make_uint4(lo[0], hi[0], lo[1], hi[1]);
        o[2 * tid + 1] = make_uint4(lo[2], hi[2], lo[3], hi[3]);
    } else if (base < n) {
        const float2* pos = (const float2*)pos4;
        const float* ang = (const float*)ang4;
        const float* mass = (const float*)mass4;
        const float2* fpos = (const float2*)fpos4;
        const float2* tpos = (const float2*)tpos4;
        for (int b = base; b < n; ++b) {
            const float2 p = pos[b];
            const float a = ang[b] - PI_2F;
            const float m = mass[b];
            const float2 r = (b < nc) ? fpos[b] : tpos[b - nc];
            const float ca = __cosf(a), sa = __sinf(a);
            const float fx = ca * r.x - sa * r.y + p.x;
            const float fy = sa * r.x + ca * r.y + p.y;
            uint2 e;
            e.x = (unsigned)__half_as_ushort(__float2half(fx)) |
                  ((unsigned)__half_as_ushort(__float2half(fy)) << 16);
            e.y = (unsigned)__half_as_ushort(__float2half(m));
            fbuf[b] = e;
        }
    }
}

// ---------------------------------------------------------------------------
// Pass 2 (k_gather): latency-bound LLC gathers -> maximize MLP.
// Each thread: 4 int4 index loads, then SIXTEEN independent 8B gathers in
// flight, 16 benign flag byte stores, then accumulate. (Round 3 had MLP=4
// and measured 0.11 gathers/cyc/CU == waves*MLP/latency; 4x MLP is the lever.)
// ---------------------------------------------------------------------------
__device__ __forceinline__ void unpack_acc(uint2 e, double& wx, double& wy, double& wm) {
    const float fx = __half2float(__ushort_as_half((unsigned short)(e.x & 0xffff)));
    const float fy = __half2float(__ushort_as_half((unsigned short)(e.x >> 16)));
    const float m  = __half2float(__ushort_as_half((unsigned short)(e.y & 0xffff)));
    wx += (double)(m * fx);
    wy += (double)(m * fy);
    wm += (double)m;
}

__global__ void k_gather(const int* __restrict__ fromb, const int* __restrict__ tob,
                         int nc, const uint2* __restrict__ fbuf,
                         unsigned char* __restrict__ flags,
                         double* __restrict__ partials) {
    const int half4  = nc >> 2;           // int4 chunks per array
    const int total4 = 2 * half4;
    const int tid = blockIdx.x * blockDim.x + threadIdx.x;
    const int nth = gridDim.x * blockDim.x;
    double wx = 0.0, wy = 0.0, wm = 0.0;

    for (int q0 = tid; q0 < total4; q0 += 4 * nth) {
        if (q0 + 3 * nth < total4) {
            // fast path: 4 int4 loads -> 16 gathers all independent
            int idx[16];
            #pragma unroll
            for (int j = 0; j < 4; ++j) {
                const int q = q0 + j * nth;
                const int4 v = (q < half4) ? ((const int4*)fromb)[q]
                                           : ((const int4*)tob)[q - half4];
                idx[4 * j]     = v.x;
                idx[4 * j + 1] = v.y;
                idx[4 * j + 2] = v.z;
                idx[4 * j + 3] = v.w;
            }
            uint2 e[16];
            #pragma unroll
            for (int j = 0; j < 16; ++j) e[j] = fbuf[idx[j]];
            #pragma unroll
            for (int j = 0; j < 16; ++j) flags[idx[j]] = 1;
            #pragma unroll
            for (int j = 0; j < 16; ++j) unpack_acc(e[j], wx, wy, wm);
        } else {
            for (int j = 0; j < 4; ++j) {
                const int q = q0 + j * nth;
                if (q >= total4) break;
                const int4 v = (q < half4) ? ((const int4*)fromb)[q]
                                           : ((const int4*)tob)[q - half4];
                const uint2 e0 = fbuf[v.x], e1 = fbuf[v.y], e2 = fbuf[v.z], e3 = fbuf[v.w];
                flags[v.x] = 1; flags[v.y] = 1; flags[v.z] = 1; flags[v.w] = 1;
                unpack_acc(e0, wx, wy, wm);
                unpack_acc(e1, wx, wy, wm);
                unpack_acc(e2, wx, wy, wm);
                unpack_acc(e3, wx, wy, wm);
            }
        }
    }
    const int tail = nc & 3;              // no-op for NC = 2^21
    if (tail && tid < 2 * tail) {
        const int base = nc - tail;
        const int idx = (tid < tail) ? fromb[base + tid] : tob[base + (tid - tail)];
        const uint2 e = fbuf[idx];
        flags[idx] = 1;
        unpack_acc(e, wx, wy, wm);
    }
    // wave shuffle reduction + cross-wave LDS
    for (int off = 32; off > 0; off >>= 1) {
        wx += __shfl_down(wx, off);
        wy += __shfl_down(wy, off);
        wm += __shfl_down(wm, off);
    }
    __shared__ double swx[4], swy[4], swm[4];
    const int lane = threadIdx.x & 63, wave = threadIdx.x >> 6;
    if (lane == 0) { swx[wave] = wx; swy[wave] = wy; swm[wave] = wm; }
    __syncthreads();
    if (threadIdx.x == 0) {
        double tx = 0.0, ty = 0.0, tm = 0.0;
        const int nw = blockDim.x >> 6;
        for (int w = 0; w < nw; ++w) { tx += swx[w]; ty += swy[w]; tm += swm[w]; }
        partials[3 * blockIdx.x]     = tx;
        partials[3 * blockIdx.x + 1] = ty;
        partials[3 * blockIdx.x + 2] = tm;
    }
}

// ---------------------------------------------------------------------------
// Pass 3 (k_final): reduce block partials, write target = sum/m_sum (float2).
// ---------------------------------------------------------------------------
__global__ void k_final(const double* __restrict__ partials, int nparts,
                        float2* __restrict__ target) {
    double sx = 0.0, sy = 0.0, sm = 0.0;
    for (int i = threadIdx.x; i < nparts; i += blockDim.x) {
        sx += partials[3 * i];
        sy += partials[3 * i + 1];
        sm += partials[3 * i + 2];
    }
    for (int off = 32; off > 0; off >>= 1) {
        sx += __shfl_down(sx, off);
        sy += __shfl_down(sy, off);
        sm += __shfl_down(sm, off);
    }
    __shared__ double swx[4], swy[4], swm[4];
    const int lane = threadIdx.x & 63, wave = threadIdx.x >> 6;
    if (lane == 0) { swx[wave] = sx; swy[wave] = sy; swm[wave] = sm; }
    __syncthreads();
    if (threadIdx.x == 0) {
        double tx = 0.0, ty = 0.0, tm = 0.0;
        const int nw = blockDim.x >> 6;
        for (int w = 0; w < nw; ++w) { tx += swx[w]; ty += swy[w]; tm += swm[w]; }
        float2 t;
        t.x = (float)(tx / tm);
        t.y = (float)(ty / tm);
        *target = t;
    }
}

// ---------------------------------------------------------------------------
// Pass 4 (k_apply): recompute f(b) exactly in f32,
// out = vel + (flag ? sdt*(target-f) : 0). Coalesced, 4 bodies/thread.
// ---------------------------------------------------------------------------
__global__ void k_apply(const float4* __restrict__ pos4, const float4* __restrict__ ang4,
                        const float4* __restrict__ fpos4, const float4* __restrict__ tpos4,
                        const float4* __restrict__ vel4,
                        const unsigned char* __restrict__ flags,
                        const float2* __restrict__ target, const float* __restrict__ stiff,
                        float4* __restrict__ out4, int n, int nc) {
    const int tid = blockIdx.x * blockDim.x + threadIdx.x;
    const int base = tid << 2;
    if (base + 3 < n) {
        const float4 p01 = pos4[2 * tid], p23 = pos4[2 * tid + 1];
        const float4 a4 = ang4[tid];
        const float4* rp = (base < nc) ? (fpos4 + 2 * tid) : (tpos4 + 2 * (tid - (nc >> 2)));
        const float4 r01 = rp[0], r23 = rp[1];
        const float4 v01 = vel4[2 * tid], v23 = vel4[2 * tid + 1];
        const unsigned fl = *(const unsigned*)(flags + base);   // 4 flag bytes
        const float2 t = *target;
        const float sdt = (*stiff) * DT;

        const float px[4] = {p01.x, p01.z, p23.x, p23.z};
        const float py[4] = {p01.y, p01.w, p23.y, p23.w};
        const float rx[4] = {r01.x, r01.z, r23.x, r23.z};
        const float ry[4] = {r01.y, r01.w, r23.y, r23.w};
        const float aa[4] = {a4.x, a4.y, a4.z, a4.w};
        float ox[4], oy[4];
        const float vx[4] = {v01.x, v01.z, v23.x, v23.z};
        const float vy[4] = {v01.y, v01.w, v23.y, v23.w};
        #pragma unroll
        for (int k = 0; k < 4; ++k) {
            const float a = aa[k] - PI_2F;
            const float ca = __cosf(a), sa = __sinf(a);
            const float fx = ca * rx[k] - sa * ry[k] + px[k];
            const float fy = sa * rx[k] + ca * ry[k] + py[k];
            const bool touched = ((fl >> (8 * k)) & 0xff) != 0;
            ox[k] = vx[k] + (touched ? sdt * (t.x - fx) : 0.0f);
            oy[k] = vy[k] + (touched ? sdt * (t.y - fy) : 0.0f);
        }
        out4[2 * tid]     = make_float4(ox[0], oy[0], ox[1], oy[1]);
        out4[2 * tid + 1] = make_float4(ox[2], oy[2], ox[3], oy[3]);
    } else if (base < n) {
        const float2* pos = (const float2*)pos4;
        const float* ang = (const float*)ang4;
        const float2* fpos = (const float2*)fpos4;
        const float2* tpos = (const float2*)tpos4;
        const float2* vel = (const float2*)vel4;
        float2* out = (float2*)out4;
        const float2 t = *target;
        const float sdt = (*stiff) * DT;
        for (int b = base; b < n; ++b) {
            const float2 p = pos[b];
            const float a = ang[b] - PI_2F;
            const float2 r = (b < nc) ? fpos[b] : tpos[b - nc];
            const float ca = __cosf(a), sa = __sinf(a);
            const float fx = ca * r.x - sa * r.y + p.x;
            const float fy = sa * r.x + ca * r.y + p.y;
            float2 o = vel[b];
            if (flags[b]) { o.x += sdt * (t.x - fx); o.y += sdt * (t.y - fy); }
            out[b] = o;
        }
    }
}

// ---------------------------------------------------------------------------
// Launch.  Inputs (setup_inputs order):
//  0 from_bodies int32[NC]  1 to_bodies int32[NC]
//  2 from_bodies_position f32[NC,2]  3 to_bodies_position f32[NC,2]
//  4 stiffness f32[1]  5 position f32[N,2]  6 angle f32[N]
//  7 mass f32[N]  8 velocity f32[N,2]      Output: f32[N,2]
//
// ws layout: [0,8) float2 target; [64,64+3*8*GB) double partials;
//            then uint2 fbuf[N]; then uchar flags[N]   (~37.8 MB total)
// ---------------------------------------------------------------------------
extern "C" void kernel_launch(void* const* d_in, const int* in_sizes, int n_in,
                              void* d_out, int out_size, void* d_ws, size_t ws_size,
                              hipStream_t stream) {
    const int NC = in_sizes[0];
    const int N  = in_sizes[7];   // mass has N elements

    char* ws = (char*)d_ws;
    float2* target   = (float2*)ws;
    double* partials = (double*)(ws + 64);
    uint2*  fbuf     = (uint2*)(ws + 64 + (size_t)GATHER_BLOCKS * 3 * sizeof(double));
    unsigned char* flags = (unsigned char*)((char*)fbuf + (size_t)N * sizeof(uint2));

    // zero only the flags (4 MB); partials/target are written unconditionally
    hipMemsetAsync(flags, 0, (size_t)N, stream);

    // pass 1: build the f16 gather table
    {
        int threads = (N + 3) >> 2;
        int blocks = (threads + BT - 1) / BT;
        k_prep<<<blocks, BT, 0, stream>>>(
            (const float4*)d_in[5], (const float4*)d_in[6], (const float4*)d_in[7],
            (const float4*)d_in[2], (const float4*)d_in[3], fbuf, N, NC);
    }
    // pass 2: gather (MLP=16) + flag scatter + partial sums
    k_gather<<<GATHER_BLOCKS, BT, 0, stream>>>(
        (const int*)d_in[0], (const int*)d_in[1], NC, fbuf, flags, partials);
    // pass 3: final reduce -> target
    k_final<<<1, BT, 0, stream>>>(partials, GATHER_BLOCKS, target);
    // pass 4: apply
    {
        int threads = (N + 3) >> 2;
        int blocks = (threads + BT - 1) / BT;
        k_apply<<<blocks, BT, 0, stream>>>(
            (const float4*)d_in[5], (const float4*)d_in[6],
            (const float4*)d_in[2], (const float4*)d_in[3],
            (const float4*)d_in[8], flags, (const float2*)target,
            (const float*)d_in[4], (float4*)d_out, N, NC);
    }
}